// Round 3
// baseline (196.197 us; speedup 1.0000x reference)
//
#include <hip/hip_runtime.h>
#include <hip/hip_bf16.h>

typedef __attribute__((ext_vector_type(8))) short s16x8;
typedef __attribute__((ext_vector_type(4))) float f32x4;
typedef unsigned short u16;

#define NB 16
#define NK 256
#define APP 768
#define DKK 96
#define NR 8
#define QSCALE 0.10206207261596575f   // 1/sqrt(96), folded into Q at projection

__device__ __forceinline__ u16 f2bf(float f) {
  union { float f; unsigned int u; } v; v.f = f;
  unsigned int x = v.u;
  x += 0x7fffu + ((x >> 16) & 1u);
  return (u16)(x >> 16);
}
__device__ __forceinline__ float bf2f(u16 h) {
  union { unsigned int u; float f; } v; v.u = ((unsigned int)h) << 16;
  return v.f;
}
__device__ __forceinline__ void gload_lds16(const void* g, void* l) {
  __builtin_amdgcn_global_load_lds(
      (const __attribute__((address_space(1))) unsigned int*)g,
      (__attribute__((address_space(3))) unsigned int*)l, 16, 0, 0);
}

// ---------------------------------------------------------------------------
// Kernel 0: convert f_a and the 3 projection weights to bf16.
// ---------------------------------------------------------------------------
__global__ __launch_bounds__(256) void conv_kernel(
    const float* __restrict__ fa,
    const float* __restrict__ WKw, const float* __restrict__ WQw,
    const float* __restrict__ WVw,
    u16* __restrict__ fab, u16* __restrict__ Wb)
{
  const int idx = blockIdx.x * 256 + threadIdx.x;
  const int faCh = NB * NK * APP / 8;      // 393216
  const int wCh  = NR * DKK * APP / 8;     // 73728 per weight array
  const float* src; u16* dst;
  if (idx < faCh) {
    src = fa + (size_t)idx * 8;
    dst = fab + (size_t)idx * 8;
  } else {
    int o = idx - faCh;
    int a = o / wCh;
    int oo = o - a * wCh;
    const float* wsrc = a == 0 ? WKw : (a == 1 ? WQw : WVw);
    src = wsrc + (size_t)oo * 8;
    dst = Wb + (size_t)a * (NR * DKK * APP) + (size_t)oo * 8;
  }
  float4 v0 = *(const float4*)src;
  float4 v1 = *(const float4*)(src + 4);
  s16x8 ov = {(short)f2bf(v0.x),(short)f2bf(v0.y),(short)f2bf(v0.z),(short)f2bf(v0.w),
              (short)f2bf(v1.x),(short)f2bf(v1.y),(short)f2bf(v1.z),(short)f2bf(v1.w)};
  *(s16x8*)dst = ov;
}

// ---------------------------------------------------------------------------
// Kernel 1 (FUSED): proj-GEMM blocks + wg-bias blocks in one grid, interleaved
// 9:16 per 25-block group so each CU co-hosts MFMA-bound proj waves and
// HBM-streaming wg waves (grid-level compute/memory overlap).
//
// proj: C[m,c] = fab[m,:].Wb[c,:] + bias.  128x128 tile, BK=64, 4 waves.
//   global_load_lds w=16, both-sides XOR swizzle.  wk,wq row-major (Q
//   pre-scaled), wvT transposed [r][b][k][m] with packed ushort4 stores.
// wg: lb2[r][b][m][n] = log(max(pos.WGw[r]+WGb[r],1e-6)), weights held in
//   registers (static-index array), nontemporal pos loads.
// ---------------------------------------------------------------------------
#define PROJ_BLKS 576
#define WG_BLKS 1024

__global__ __launch_bounds__(256) void fused_kernel(
    const u16* __restrict__ fab, const u16* __restrict__ Wb,
    const float* __restrict__ WKb, const float* __restrict__ WQb,
    const float* __restrict__ WVb,
    u16* __restrict__ wk, u16* __restrict__ wq, u16* __restrict__ wvT,
    const float* __restrict__ pos,
    const float* __restrict__ WGw, const float* __restrict__ WGb,
    u16* __restrict__ lb2)
{
  __shared__ u16 As[128 * 64];   // proj path only (16 KB)
  __shared__ u16 Bs[128 * 64];
  const int t = threadIdx.x;
  const int bid = blockIdx.x;
  const int grp = bid / 25, rem = bid % 25;

  if (rem < 9) {
    // ----------------------- proj path -----------------------
    const int pb = grp * 9 + rem;          // 0..575
    const int lane = t & 63, w = t >> 6;
    const int c = lane & 15, g = lane >> 4;
    const int wr = w >> 1, wc = w & 1;
    const int m0 = (pb & 31) * 128;
    const int ct = pb >> 5;                // 0..17
    const int c0 = ct * 128;

    f32x4 acc[4][4] = {};

    for (int k0 = 0; k0 < APP; k0 += 64) {
      __syncthreads();
      #pragma unroll
      for (int i = 0; i < 4; ++i) {
        int n = t + i * 256;               // chunk id, 0..1023
        int row = n >> 3, cg = n & 7;
        int scg = cg ^ (row & 7);          // pre-swizzled global col-group
        gload_lds16(fab + (size_t)(m0 + row) * APP + k0 + scg * 8, As + n * 8);
        gload_lds16(Wb  + (size_t)(c0 + row) * APP + k0 + scg * 8, Bs + n * 8);
      }
      __syncthreads();
      #pragma unroll
      for (int kc = 0; kc < 2; ++kc) {
        s16x8 af[4], bfr[4];
        #pragma unroll
        for (int i = 0; i < 4; ++i) {
          int arow = wr * 64 + i * 16 + c;
          af[i]  = *(const s16x8*)(As + (((arow << 3) | ((kc * 4 + g) ^ (arow & 7))) << 3));
          int brow = wc * 64 + i * 16 + c;
          bfr[i] = *(const s16x8*)(Bs + (((brow << 3) | ((kc * 4 + g) ^ (brow & 7))) << 3));
        }
        #pragma unroll
        for (int mi = 0; mi < 4; ++mi)
          #pragma unroll
          for (int ni = 0; ni < 4; ++ni)
            acc[mi][ni] = __builtin_amdgcn_mfma_f32_16x16x32_bf16(af[mi], bfr[ni], acc[mi][ni], 0, 0, 0);
      }
    }

    const int arr = ct / 6;                // 0=K 1=Q 2=V
    const int cw0 = c0 - arr * APP;
    const float* bp = arr == 0 ? WKb : (arr == 1 ? WQb : WVb);

    #pragma unroll
    for (int mi = 0; mi < 4; ++mi)
      #pragma unroll
      for (int ni = 0; ni < 4; ++ni) {
        int clw = cw0 + wc * 64 + ni * 16 + c;
        float bias = bp[clw];
        int rr = clw / DKK, kk = clw - rr * DKK;
        int mb = m0 + wr * 64 + mi * 16 + g * 4;     // 4 consecutive m
        int bi = mb >> 8, tt = mb & 255;
        if (arr == 2) {
          ushort4 pk;
          pk.x = f2bf(acc[mi][ni][0] + bias);
          pk.y = f2bf(acc[mi][ni][1] + bias);
          pk.z = f2bf(acc[mi][ni][2] + bias);
          pk.w = f2bf(acc[mi][ni][3] + bias);
          *(ushort4*)&wvT[(((size_t)rr * NB + bi) * DKK + kk) * NK + tt] = pk;
        } else {
          u16* op = arr == 0 ? wk : wq;
          #pragma unroll
          for (int e = 0; e < 4; ++e) {
            float val = acc[mi][ni][e] + bias;
            if (arr == 1) val *= QSCALE;
            op[(((size_t)rr * NB + bi) * NK + tt + e) * DKK + kk] = f2bf(val);
          }
        }
      }
  } else {
    // ----------------------- wg path -----------------------
    const int wb = grp * 16 + (rem - 9);   // 0..1023
    const int n0 = (wb & 7) * 32;
    const int m0 = ((wb >> 3) & 7) * 32;
    const int b = wb >> 6;
    const int slot = t >> 3, l8 = t & 7;

    // weights in registers (static indices -> VGPRs, no LDS in inner loop)
    float wreg[8][12];
    #pragma unroll
    for (int rr = 0; rr < 8; ++rr)
      #pragma unroll
      for (int u = 0; u < 12; ++u)
        wreg[rr][u] = WGw[rr * 96 + l8 * 12 + u];
    const float wb_b = WGb[l8];

    for (int i = 0; i < 32; ++i) {
      const float* p = pos + (((size_t)(b * NK + m0 + i) * NK) + n0 + slot) * 96 + l8 * 12;
      f32x4 q0 = __builtin_nontemporal_load((const f32x4*)p);
      f32x4 q1 = __builtin_nontemporal_load((const f32x4*)(p + 4));
      f32x4 q2 = __builtin_nontemporal_load((const f32x4*)(p + 8));
      float pv[12] = {q0[0],q0[1],q0[2],q0[3], q1[0],q1[1],q1[2],q1[3],
                      q2[0],q2[1],q2[2],q2[3]};
      float acc[8] = {0.f,0.f,0.f,0.f,0.f,0.f,0.f,0.f};
      #pragma unroll
      for (int u = 0; u < 12; ++u) {
        float x = pv[u];
        #pragma unroll
        for (int rr = 0; rr < 8; ++rr) acc[rr] += x * wreg[rr][u];
      }
      #pragma unroll
      for (int rr = 0; rr < 8; ++rr) {
        acc[rr] += __shfl_xor(acc[rr], 1);
        acc[rr] += __shfl_xor(acc[rr], 2);
        acc[rr] += __shfl_xor(acc[rr], 4);
      }
      // static select tree (no dynamic register indexing)
      float v = l8 < 4 ? (l8 < 2 ? (l8 == 0 ? acc[0] : acc[1])
                                 : (l8 == 2 ? acc[2] : acc[3]))
                       : (l8 < 6 ? (l8 == 4 ? acc[4] : acc[5])
                                 : (l8 == 6 ? acc[6] : acc[7]));
      v = __logf(fmaxf(v + wb_b, 1e-6f));
      lb2[(((size_t)l8 * NB + b) * NK + m0 + i) * NK + n0 + slot] = f2bf(v);
    }
  }
}

// ---------------------------------------------------------------------------
// Kernel 2: attention.  512 blocks (4 n-blocks x 16 b x 8 r), 4 waves each,
// wave owns 16 query rows (n).  Zero __syncthreads; bias rows preloaded to
// registers before the QK MFMA chain.
// ---------------------------------------------------------------------------
__global__ __launch_bounds__(256) void attn_kernel(
    const u16* __restrict__ wk, const u16* __restrict__ wq,
    const u16* __restrict__ wvT, const u16* __restrict__ lb2,
    const float* __restrict__ fa, float* __restrict__ out)
{
  __shared__ u16 Ps[4][16][40];   // per-wave P chunk [16 n][32 m]
  const int t = threadIdx.x;
  const int w = t >> 6, lane = t & 63;
  const int c = lane & 15, g = lane >> 4;
  const int b = blockIdx.y, r = blockIdx.z;
  const int nb = blockIdx.x * 64 + w * 16;

  const size_t hb = (size_t)r * NB + b;
  const u16* Qr = wq + (hb * NK + nb + c) * DKK + g * 8;
  const u16* Kr = wk + (hb * NK + c) * DKK + g * 8;
  const u16* Vr = wvT + (hb * DKK + c) * NK + g * 8;
  const u16* Br = lb2 + hb * NK * NK + (size_t)c * NK + nb + g * 4;

  s16x8 qf[3];
  #pragma unroll
  for (int kc = 0; kc < 3; ++kc) qf[kc] = *(const s16x8*)(Qr + kc * 32);

  // preload all 16 bias quads (independent loads, breaks per-mt serialization)
  ushort4 bbr[16];
  #pragma unroll
  for (int mt = 0; mt < 16; ++mt)
    bbr[mt] = *(const ushort4*)(Br + (size_t)mt * 16 * NK);

  // S[n = nb+g*4+e][m = mt*16+c], Q pre-scaled, bias as MFMA C-input
  f32x4 S[16];
  #pragma unroll
  for (int mt = 0; mt < 16; ++mt) {
    f32x4 sa = {bf2f(bbr[mt].x), bf2f(bbr[mt].y), bf2f(bbr[mt].z), bf2f(bbr[mt].w)};
    #pragma unroll
    for (int kc = 0; kc < 3; ++kc) {
      s16x8 kf = *(const s16x8*)(Kr + (size_t)mt * 16 * DKK + kc * 32);
      sa = __builtin_amdgcn_mfma_f32_16x16x32_bf16(qf[kc], kf, sa, 0, 0, 0);
    }
    S[mt] = sa;
  }

  // softmax over m: 16 in-lane + shfl_xor over the 16 c-lanes
  float rinv[4];
  #pragma unroll
  for (int e = 0; e < 4; ++e) {
    float mx = S[0][e];
    #pragma unroll
    for (int mt = 1; mt < 16; ++mt) mx = fmaxf(mx, S[mt][e]);
    mx = fmaxf(mx, __shfl_xor(mx, 1));
    mx = fmaxf(mx, __shfl_xor(mx, 2));
    mx = fmaxf(mx, __shfl_xor(mx, 4));
    mx = fmaxf(mx, __shfl_xor(mx, 8));
    float sm = 0.f;
    #pragma unroll
    for (int mt = 0; mt < 16; ++mt) {
      float p = __expf(S[mt][e] - mx);
      S[mt][e] = p;
      sm += p;
    }
    sm += __shfl_xor(sm, 1);
    sm += __shfl_xor(sm, 2);
    sm += __shfl_xor(sm, 4);
    sm += __shfl_xor(sm, 8);
    rinv[e] = 1.f / sm;
  }

  // PV in 8 chunks of 32 m: stage P chunk (per-wave LDS), MFMA vs wvT frags
  f32x4 o[6];
  #pragma unroll
  for (int ki = 0; ki < 6; ++ki) o[ki] = (f32x4){0.f, 0.f, 0.f, 0.f};

  #pragma unroll
  for (int mc = 0; mc < 8; ++mc) {
    #pragma unroll
    for (int e = 0; e < 4; ++e) {
      Ps[w][g * 4 + e][c]      = f2bf(S[2 * mc][e]);
      Ps[w][g * 4 + e][16 + c] = f2bf(S[2 * mc + 1][e]);
    }
    s16x8 pa = *(const s16x8*)&Ps[w][c][g * 8];
    #pragma unroll
    for (int ki = 0; ki < 6; ++ki) {
      s16x8 vf = *(const s16x8*)(Vr + (size_t)(ki * 16) * NK + mc * 32);
      o[ki] = __builtin_amdgcn_mfma_f32_16x16x32_bf16(pa, vf, o[ki], 0, 0, 0);
    }
  }

  // epilogue: normalize, residual, fp32 store
  #pragma unroll
  for (int ki = 0; ki < 6; ++ki)
    #pragma unroll
    for (int e = 0; e < 4; ++e) {
      int n = nb + g * 4 + e;
      size_t adr = ((size_t)b * NK + n) * (NR * DKK) + r * DKK + ki * 16 + c;
      out[adr] = o[ki][e] * rinv[e] + fa[adr];
    }
}

extern "C" void kernel_launch(void* const* d_in, const int* in_sizes, int n_in,
                              void* d_out, int out_size, void* d_ws, size_t ws_size,
                              hipStream_t stream) {
  (void)in_sizes; (void)n_in; (void)out_size; (void)ws_size;
  const float* fa  = (const float*)d_in[0];
  const float* pos = (const float*)d_in[1];
  const float* WGw = (const float*)d_in[2];
  const float* WGb = (const float*)d_in[3];
  const float* WKw = (const float*)d_in[4];
  const float* WKb = (const float*)d_in[5];
  const float* WQw = (const float*)d_in[6];
  const float* WQb = (const float*)d_in[7];
  const float* WVw = (const float*)d_in[8];
  const float* WVb = (const float*)d_in[9];
  float* outp = (float*)d_out;

  const size_t faN = (size_t)NB * NK * APP;       // 3,145,728
  const size_t wN  = (size_t)3 * NR * DKK * APP;  // 1,769,472
  const size_t kqv = (size_t)NR * NB * NK * DKK;  // 3,145,728
  u16* fab = (u16*)d_ws;
  u16* Wb  = fab + faN;
  u16* wk  = Wb + wN;
  u16* wq  = wk + kqv;
  u16* wvT = wq + kqv;
  u16* lb2 = wvT + kqv;

  hipLaunchKernelGGL(conv_kernel, dim3(2400), dim3(256), 0, stream,
                     fa, WKw, WQw, WVw, fab, Wb);
  hipLaunchKernelGGL(fused_kernel, dim3(PROJ_BLKS + WG_BLKS), dim3(256), 0, stream,
                     fab, Wb, WKb, WQb, WVb, wk, wq, wvT, pos, WGw, WGb, lb2);
  hipLaunchKernelGGL(attn_kernel, dim3(4, NB, NR), dim3(256), 0, stream,
                     wk, wq, wvT, lb2, fa, outp);
}